// Round 3
// baseline (4652.722 us; speedup 1.0000x reference)
//
#include <hip/hip_runtime.h>
#include <math.h>

#define BB     4
#define LLEN   409
#define DMODEL 192
#define DINNER 384
#define DSTATE 16
#define DRANK  12
#define KCONV  4
#define NLAYER 24
#define NROW   (BB*LLEN)      /* 1636 */
#define EPSF   1e-5f
#define CH2    16             /* scan chunk length */
#define NCH2   26             /* 16*26=416 >= 409 */

__device__ __forceinline__ float siluf(float x){ return x/(1.f+__expf(-x)); }
__device__ __forceinline__ float softplusf(float x){ return (x>20.f)? x : log1pf(__expf(x)); }

// ---------------- prep kernels ----------------
__global__ void k_init(const float* __restrict__ t, float* __restrict__ r, int n){
  int i = blockIdx.x*256+threadIdx.x;
  if (i<n) r[i]=t[i];
}

// dst[l][c][r] = src[l][r][c]
__global__ void k_transpose(const float* __restrict__ src, float* __restrict__ dst, int R, int C){
  int total = NLAYER*R*C;
  for (int i = blockIdx.x*blockDim.x+threadIdx.x; i<total; i += gridDim.x*blockDim.x){
    int l = i/(R*C); int rem = i%(R*C); int r = rem/C; int c = rem%C;
    dst[((size_t)l*C + c)*R + r] = src[i];
  }
}

// AnT[l][n][d] = -exp(A_log[l][d][n])
__global__ void k_negexpT(const float* __restrict__ a, float* __restrict__ o, int n){
  int i = blockIdx.x*256+threadIdx.x;
  if (i<n){
    int l = i/(DINNER*DSTATE); int rem = i%(DINNER*DSTATE);
    int d = rem/DSTATE, nn = rem%DSTATE;
    o[(size_t)l*DINNER*DSTATE + nn*DINNER + d] = -expf(a[i]);
  }
}

// ---------------- layer kernels ----------------
// norm + in_proj: TM=16, TN=128; grid (103, 6)
__global__ __launch_bounds__(256) void k_normin(const float* __restrict__ residual,
    const float* __restrict__ norm_w, const float* __restrict__ Wt,
    float* __restrict__ xz){
  __shared__ __align__(16) float a_lds[DMODEL*20];
  __shared__ float rs_s[16];
  int tid = threadIdx.x, r0 = blockIdx.x*16, c0 = blockIdx.y*128;
  #pragma unroll
  for (int s=0;s<12;s++){
    int idx = tid + s*256; int i = idx/DMODEL, k = idx%DMODEL; int row = r0+i;
    a_lds[k*20+i] = (row<NROW)? residual[(size_t)row*DMODEL+k] : 0.f;
  }
  __syncthreads();
  int wv = tid>>6, lane = tid&63;
  {
    float ss[4] = {0.f,0.f,0.f,0.f};
    #pragma unroll
    for (int q=0;q<3;q++){
      int k = lane + q*64;
      #pragma unroll
      for (int r=0;r<4;r++){ float v = a_lds[k*20 + wv*4 + r]; ss[r] += v*v; }
    }
    #pragma unroll
    for (int r=0;r<4;r++){
      float s = ss[r];
      #pragma unroll
      for (int off=1; off<64; off<<=1) s += __shfl_xor(s, off, 64);
      if (lane==0) rs_s[wv*4+r] = rsqrtf(s/(float)DMODEL + EPSF);
    }
  }
  __syncthreads();
  #pragma unroll
  for (int s=0;s<12;s++){
    int idx = tid + s*256; int k = idx>>4, i = idx&15;
    a_lds[k*20+i] *= rs_s[i]*norm_w[k];
  }
  __syncthreads();
  int rh = tid>>7, jj = tid&127;
  int j = c0 + jj;
  float acc[8];
  #pragma unroll
  for (int i=0;i<8;i++) acc[i]=0.f;
  #pragma unroll 2
  for (int k=0;k<DMODEL;k++){
    float w = Wt[(size_t)k*768 + j];
    float4 a0 = *reinterpret_cast<const float4*>(&a_lds[k*20 + rh*8]);
    float4 a1 = *reinterpret_cast<const float4*>(&a_lds[k*20 + rh*8 + 4]);
    acc[0]+=a0.x*w; acc[1]+=a0.y*w; acc[2]+=a0.z*w; acc[3]+=a0.w*w;
    acc[4]+=a1.x*w; acc[5]+=a1.y*w; acc[6]+=a1.z*w; acc[7]+=a1.w*w;
  }
  #pragma unroll
  for (int i=0;i<8;i++){
    int row = r0 + rh*8 + i;
    if (row<NROW) xz[(size_t)row*768 + j] = acc[i];
  }
}

// causal depthwise conv + bias + silu, float4 over d; grid (ceil(NROW*96/256), 2)
__global__ __launch_bounds__(256) void k_conv(const float* __restrict__ xz,
    const float* __restrict__ cwf, const float* __restrict__ cbf,
    const float* __restrict__ cwb, const float* __restrict__ cbb,
    float* __restrict__ xf_f, float* __restrict__ xf_b){
  int idx = blockIdx.x*256 + threadIdx.x;
  if (idx >= NROW*(DINNER/4)) return;
  int d4 = (idx % (DINNER/4))*4; int bl = idx / (DINNER/4);
  int b = bl / LLEN; int l = bl % LLEN;
  int dir = blockIdx.y;
  const float* cw = dir? cwb : cwf;
  const float* cb = dir? cbb : cbf;
  float4 w0 = *reinterpret_cast<const float4*>(&cw[(d4+0)*KCONV]);
  float4 w1 = *reinterpret_cast<const float4*>(&cw[(d4+1)*KCONV]);
  float4 w2 = *reinterpret_cast<const float4*>(&cw[(d4+2)*KCONV]);
  float4 w3 = *reinterpret_cast<const float4*>(&cw[(d4+3)*KCONV]);
  float4 acc = *reinterpret_cast<const float4*>(&cb[d4]);
  const float* wa0 = (const float*)&w0; const float* wa1 = (const float*)&w1;
  const float* wa2 = (const float*)&w2; const float* wa3 = (const float*)&w3;
  #pragma unroll
  for (int k=0;k<KCONV;k++){
    int o = dir? (LLEN-1-l-k+3) : (l-3+k);
    bool ok = dir? (l+k>=3) : (o>=0);
    if (ok){
      float4 x = *reinterpret_cast<const float4*>(&xz[((size_t)(b*LLEN+o))*768 + d4]);
      acc.x += wa0[k]*x.x; acc.y += wa1[k]*x.y; acc.z += wa2[k]*x.z; acc.w += wa3[k]*x.w;
    }
  }
  float* out = dir? xf_b : xf_f;
  float4 r; r.x = siluf(acc.x); r.y = siluf(acc.y); r.z = siluf(acc.z); r.w = siluf(acc.w);
  *reinterpret_cast<float4*>(&out[(size_t)bl*DINNER + d4]) = r;
}

// x_proj + dt_proj + softplus; TM=8; grid (205, 2)
__global__ __launch_bounds__(256) void k_xp(
    const float* __restrict__ xf_f, const float* __restrict__ xf_b,
    const float* __restrict__ WxpF, const float* __restrict__ WxpB,
    const float* __restrict__ WdtF, const float* __restrict__ WdtB,
    const float* __restrict__ dtbF, const float* __restrict__ dtbB,
    float* __restrict__ dtbc_f, float* __restrict__ dtbc_b,
    float* __restrict__ dt_f, float* __restrict__ dt_b){
  __shared__ __align__(16) float x_lds[DINNER*12];
  __shared__ float dtin_s[8*12];
  int dir = blockIdx.y;
  const float* xf  = dir? xf_b : xf_f;
  const float* Wxp = dir? WxpB : WxpF;
  const float* Wdt = dir? WdtB : WdtF;
  const float* dtb = dir? dtbB : dtbF;
  float* dtbc = dir? dtbc_b : dtbc_f;
  float* dtp  = dir? dt_b  : dt_f;
  int tid = threadIdx.x; int r0 = blockIdx.x*8;
  #pragma unroll
  for (int s=0;s<12;s++){
    int idx = tid + s*256; int i = idx/DINNER, k = idx%DINNER; int row = r0+i;
    x_lds[k*12+i] = (row<NROW)? xf[(size_t)row*DINNER + k] : 0.f;
  }
  __syncthreads();
  int j = tid & 63; int rg = tid >> 6;     // rows rg*2, rg*2+1
  float acc0=0.f, acc1=0.f;
  #pragma unroll 2
  for (int k=0;k<DINNER;k++){
    float w = (j<44)? Wxp[(size_t)k*44 + j] : 0.f;
    float2 a = *reinterpret_cast<const float2*>(&x_lds[k*12 + rg*2]);
    acc0 += a.x*w; acc1 += a.y*w;
  }
  {
    int i0 = rg*2, i1 = rg*2+1;
    int row0 = r0+i0, row1 = r0+i1;
    if (j<44){
      if (row0<NROW) dtbc[(size_t)row0*44 + j] = acc0;
      if (row1<NROW) dtbc[(size_t)row1*44 + j] = acc1;
    }
    if (j<12){ dtin_s[i0*12+j] = acc0; dtin_s[i1*12+j] = acc1; }
  }
  __syncthreads();
  for (int idx = tid; idx < 8*DINNER; idx += 256){
    int i = idx/DINNER, dd = idx%DINNER; int row = r0+i;
    float v = dtb[dd];
    #pragma unroll
    for (int r=0;r<12;r++) v += dtin_s[i*12+r]*Wdt[(size_t)r*DINNER+dd];
    if (row<NROW) dtp[(size_t)row*DINNER+dd] = softplusf(v);
  }
}

// scan pass 1: per-chunk transfer fn; thread = one d, 16 n-states in regs
// grid (3, BB*NCH2, 2), 128 threads
__global__ __launch_bounds__(128) void k_scan1(
    const float* __restrict__ xf_f, const float* __restrict__ xf_b,
    const float* __restrict__ dtbc_f, const float* __restrict__ dtbc_b,
    const float* __restrict__ dt_f, const float* __restrict__ dt_b,
    const float* __restrict__ anF, const float* __restrict__ anB,
    float* __restrict__ q_buf, float* __restrict__ sdt_buf){
  int dir = blockIdx.z;
  int b  = blockIdx.y / NCH2;
  int ch = blockIdx.y % NCH2;
  const float* xf   = dir? xf_b  : xf_f;
  const float* dtbc = dir? dtbc_b: dtbc_f;
  const float* dtp  = dir? dt_b  : dt_f;
  const float* an   = dir? anB   : anF;
  int t0 = ch*CH2;
  int T  = (t0+CH2<=LLEN)? CH2 : (LLEN-t0);
  int d0 = blockIdx.x*128;
  size_t base = (size_t)b*LLEN + t0;
  __shared__ float dt_s[CH2*128], u_s[CH2*128];
  __shared__ __align__(16) float B_s[CH2*16];
  int tid = threadIdx.x;
  for (int t=0;t<T;t++){
    dt_s[t*128+tid] = dtp[(base+t)*DINNER + d0 + tid];
    u_s [t*128+tid] = xf [(base+t)*DINNER + d0 + tid];
  }
  for (int idx = tid; idx < T*16; idx += 128){
    int t = idx>>4, n = idx&15;
    B_s[idx] = dtbc[(base+t)*44 + 12 + n];
  }
  __syncthreads();
  int d = d0 + tid;
  float A[16], h[16];
  #pragma unroll
  for (int n=0;n<16;n++){ A[n] = an[n*DINNER + d]; h[n] = 0.f; }
  float sdt = 0.f;
  for (int t=0;t<T;t++){
    float dtv = dt_s[t*128+tid];
    float du  = dtv * u_s[t*128+tid];
    float Bv[16];
    #pragma unroll
    for (int q=0;q<4;q++) *reinterpret_cast<float4*>(&Bv[q*4]) =
        *reinterpret_cast<const float4*>(&B_s[t*16 + q*4]);
    #pragma unroll
    for (int n=0;n<16;n++) h[n] = h[n]*__expf(dtv*A[n]) + du*Bv[n];
    sdt += dtv;
  }
  size_t ci = ((size_t)dir*BB + b)*NCH2 + ch;
  float* qo = &q_buf[(ci*DINNER + d)*DSTATE];
  #pragma unroll
  for (int q=0;q<4;q++) *reinterpret_cast<float4*>(&qo[q*4]) =
      make_float4(h[q*4+0], h[q*4+1], h[q*4+2], h[q*4+3]);
  sdt_buf[ci*DINNER + d] = sdt;
}

// carry fold (in place): q_buf[ch] <- carry-in state for chunk ch
// grid (192), 256 threads; thread = (dir,b,d,n)
__global__ __launch_bounds__(256) void k_carry(
    const float* __restrict__ anF, const float* __restrict__ anB,
    float* __restrict__ q_buf, const float* __restrict__ sdt_buf){
  int g = blockIdx.x*256 + threadIdx.x;
  int n = g & 15; int r1 = g >> 4;
  int d = r1 % DINNER; int r2 = r1 / DINNER;
  int b = r2 & 3; int dir = r2 >> 2;
  const float* an = dir? anB : anF;
  float A = an[n*DINNER + d];
  size_t sbase = ((size_t)dir*BB + b)*NCH2;
  float h = 0.f;
  for (int cc=0; cc<NCH2; cc++){
    size_t qi = ((sbase+cc)*DINNER + d)*DSTATE + n;
    float qv = q_buf[qi];
    float sv = sdt_buf[(sbase+cc)*DINNER + d];
    q_buf[qi] = h;
    h = qv + __expf(A*sv)*h;
  }
}

// scan pass 2: replay chunk from carry-in, emit y; grid (3, BB*NCH2, 2), 128 thr
__global__ __launch_bounds__(128) void k_scan2(
    const float* __restrict__ xf_f, const float* __restrict__ xf_b,
    const float* __restrict__ dtbc_f, const float* __restrict__ dtbc_b,
    const float* __restrict__ dt_f, const float* __restrict__ dt_b,
    const float* __restrict__ anF, const float* __restrict__ anB,
    const float* __restrict__ DpF, const float* __restrict__ DpB,
    const float* __restrict__ q_buf,
    float* __restrict__ y_fo, float* __restrict__ y_bo){
  int dir = blockIdx.z;
  int b  = blockIdx.y / NCH2;
  int ch = blockIdx.y % NCH2;
  const float* xf   = dir? xf_b  : xf_f;
  const float* dtbc = dir? dtbc_b: dtbc_f;
  const float* dtp  = dir? dt_b  : dt_f;
  const float* an   = dir? anB   : anF;
  const float* Dp   = dir? DpB   : DpF;
  float* y = dir? y_bo : y_fo;
  int t0 = ch*CH2;
  int T  = (t0+CH2<=LLEN)? CH2 : (LLEN-t0);
  int d0 = blockIdx.x*128;
  size_t base = (size_t)b*LLEN + t0;
  __shared__ float dt_s[CH2*128], u_s[CH2*128];
  __shared__ __align__(16) float B_s[CH2*16], C_s[CH2*16];
  int tid = threadIdx.x;
  for (int t=0;t<T;t++){
    dt_s[t*128+tid] = dtp[(base+t)*DINNER + d0 + tid];
    u_s [t*128+tid] = xf [(base+t)*DINNER + d0 + tid];
  }
  for (int idx = tid; idx < T*16; idx += 128){
    int t = idx>>4, n = idx&15;
    B_s[idx] = dtbc[(base+t)*44 + 12 + n];
    C_s[idx] = dtbc[(base+t)*44 + 28 + n];
  }
  __syncthreads();
  int d = d0 + tid;
  size_t ci = ((size_t)dir*BB + b)*NCH2 + ch;
  const float* qi = &q_buf[(ci*DINNER + d)*DSTATE];
  float A[16], h[16];
  #pragma unroll
  for (int q=0;q<4;q++){
    float4 hv = *reinterpret_cast<const float4*>(&qi[q*4]);
    h[q*4+0]=hv.x; h[q*4+1]=hv.y; h[q*4+2]=hv.z; h[q*4+3]=hv.w;
  }
  #pragma unroll
  for (int n=0;n<16;n++) A[n] = an[n*DINNER + d];
  float Dd = Dp[d];
  for (int t=0;t<T;t++){
    float dtv = dt_s[t*128+tid];
    float u   = u_s [t*128+tid];
    float du  = dtv*u;
    float Bv[16], Cv[16];
    #pragma unroll
    for (int q=0;q<4;q++){
      *reinterpret_cast<float4*>(&Bv[q*4]) = *reinterpret_cast<const float4*>(&B_s[t*16+q*4]);
      *reinterpret_cast<float4*>(&Cv[q*4]) = *reinterpret_cast<const float4*>(&C_s[t*16+q*4]);
    }
    float y0=0.f, y1=0.f, y2=0.f, y3=0.f;
    #pragma unroll
    for (int n=0;n<16;n+=4){
      h[n+0] = h[n+0]*__expf(dtv*A[n+0]) + du*Bv[n+0];
      h[n+1] = h[n+1]*__expf(dtv*A[n+1]) + du*Bv[n+1];
      h[n+2] = h[n+2]*__expf(dtv*A[n+2]) + du*Bv[n+2];
      h[n+3] = h[n+3]*__expf(dtv*A[n+3]) + du*Bv[n+3];
      y0 += h[n+0]*Cv[n+0]; y1 += h[n+1]*Cv[n+1];
      y2 += h[n+2]*Cv[n+2]; y3 += h[n+3]*Cv[n+3];
    }
    y[(base+t)*DINNER + d] = (y0+y1)+(y2+y3) + u*Dd;
  }
}

// gate + out_proj, residual +=; TM=8, TN=64; grid (205, 3)
__global__ __launch_bounds__(256) void k_out(
    const float* __restrict__ y_f, const float* __restrict__ y_b,
    const float* __restrict__ xz, const float* __restrict__ Wt,
    float* __restrict__ residual){
  __shared__ __align__(16) float a_lds[DINNER*12];
  int tid = threadIdx.x; int r0 = blockIdx.x*8; int c0 = blockIdx.y*64;
  #pragma unroll
  for (int s=0;s<12;s++){
    int idx = tid + s*256; int i = idx/DINNER, k = idx%DINNER; int row = r0+i;
    float v = 0.f;
    if (row<NROW){
      int b = row/LLEN, l = row%LLEN;
      float yf = y_f[(size_t)row*DINNER+k];
      float yb = y_b[((size_t)(b*LLEN+(LLEN-1-l)))*DINNER+k];
      float z  = xz[(size_t)row*768 + DINNER + k];
      v = (yf+yb)*siluf(z)*0.5f;
    }
    a_lds[k*12+i] = v;
  }
  __syncthreads();
  int j = tid & 63; int rg = tid >> 6;   // rows rg*2, rg*2+1
  float acc0=0.f, acc1=0.f;
  #pragma unroll 2
  for (int k=0;k<DINNER;k++){
    float w = Wt[(size_t)k*DMODEL + c0 + j];
    float2 a = *reinterpret_cast<const float2*>(&a_lds[k*12 + rg*2]);
    acc0 += a.x*w; acc1 += a.y*w;
  }
  int row0 = r0 + rg*2, row1 = row0+1;
  if (row0<NROW) residual[(size_t)row0*DMODEL + c0 + j] += acc0;
  if (row1<NROW) residual[(size_t)row1*DMODEL + c0 + j] += acc1;
}

// final RMSNorm -> d_out
__global__ __launch_bounds__(256) void k_final(const float* __restrict__ residual,
    const float* __restrict__ nfw, float* __restrict__ out){
  int wv = threadIdx.x>>6, lane = threadIdx.x&63;
  int row = blockIdx.x*4 + wv;
  if (row >= NROW) return;
  float v[3]; float s = 0.f;
  #pragma unroll
  for (int q=0;q<3;q++){ v[q] = residual[(size_t)row*DMODEL + lane + q*64]; s += v[q]*v[q]; }
  #pragma unroll
  for (int off=1; off<64; off<<=1) s += __shfl_xor(s, off, 64);
  float sc = rsqrtf(s/(float)DMODEL + EPSF);
  #pragma unroll
  for (int q=0;q<3;q++) out[(size_t)row*DMODEL + lane + q*64] = v[q]*sc*nfw[lane + q*64];
}

// ---------------- host ----------------
extern "C" void kernel_launch(void* const* d_in, const int* in_sizes, int n_in,
                              void* d_out, int out_size, void* d_ws, size_t ws_size,
                              hipStream_t stream){
  const float* tokens     = (const float*)d_in[0];
  const float* norm_w     = (const float*)d_in[1];
  const float* in_proj_w  = (const float*)d_in[2];
  const float* conv_w     = (const float*)d_in[3];
  const float* conv_b     = (const float*)d_in[4];
  const float* conv_w_b   = (const float*)d_in[5];
  const float* conv_b_b   = (const float*)d_in[6];
  const float* x_proj_w   = (const float*)d_in[7];
  const float* x_proj_w_b = (const float*)d_in[8];
  const float* dt_proj_w  = (const float*)d_in[9];
  const float* dt_bias    = (const float*)d_in[10];
  const float* dt_proj_w_b= (const float*)d_in[11];
  const float* dt_bias_b  = (const float*)d_in[12];
  const float* A_log      = (const float*)d_in[13];
  const float* A_log_b    = (const float*)d_in[14];
  const float* D_param    = (const float*)d_in[15];
  const float* D_param_b  = (const float*)d_in[16];
  const float* out_proj_w = (const float*)d_in[17];
  const float* norm_f_w   = (const float*)d_in[18];

  float* ws = (float*)d_ws;
  size_t off = 0;
  float* residual = ws + off; off += (size_t)NROW*DMODEL;
  float* xz       = ws + off; off += (size_t)NROW*768;
  float* xf_f     = ws + off; off += (size_t)NROW*DINNER;
  float* xf_b     = ws + off; off += (size_t)NROW*DINNER;
  float* dtbc_f   = ws + off; off += (size_t)NROW*44;
  float* dtbc_b   = ws + off; off += (size_t)NROW*44;
  float* dt_f     = ws + off; off += (size_t)NROW*DINNER;
  float* dt_b     = ws + off; off += (size_t)NROW*DINNER;
  float* y_f      = ws + off; off += (size_t)NROW*DINNER;
  float* y_b      = ws + off; off += (size_t)NROW*DINNER;
  float* q_buf    = ws + off; off += (size_t)2*BB*NCH2*DINNER*DSTATE;
  float* sdt_buf  = ws + off; off += (size_t)2*BB*NCH2*DINNER;
  float* WtIn     = ws + off; off += (size_t)NLAYER*DMODEL*768;
  float* WtXpF    = ws + off; off += (size_t)NLAYER*DINNER*44;
  float* WtXpB    = ws + off; off += (size_t)NLAYER*DINNER*44;
  float* WtDtF    = ws + off; off += (size_t)NLAYER*DRANK*DINNER;
  float* WtDtB    = ws + off; off += (size_t)NLAYER*DRANK*DINNER;
  float* WtOut    = ws + off; off += (size_t)NLAYER*DINNER*DMODEL;
  float* AnTF     = ws + off; off += (size_t)NLAYER*DINNER*DSTATE;
  float* AnTB     = ws + off; off += (size_t)NLAYER*DINNER*DSTATE;
  if (off*sizeof(float) > ws_size) return;   // workspace too small: fail loudly

  // prep
  k_init<<<dim3((NROW*DMODEL+255)/256),256,0,stream>>>(tokens, residual, NROW*DMODEL);
  k_transpose<<<2048,256,0,stream>>>(in_proj_w,  WtIn,  768, DMODEL);
  k_transpose<<<1024,256,0,stream>>>(x_proj_w,   WtXpF, 44,  DINNER);
  k_transpose<<<1024,256,0,stream>>>(x_proj_w_b, WtXpB, 44,  DINNER);
  k_transpose<<<512, 256,0,stream>>>(dt_proj_w,  WtDtF, DINNER, DRANK);
  k_transpose<<<512, 256,0,stream>>>(dt_proj_w_b,WtDtB, DINNER, DRANK);
  k_transpose<<<2048,256,0,stream>>>(out_proj_w, WtOut, DMODEL, DINNER);
  k_negexpT<<<dim3((NLAYER*DINNER*DSTATE+255)/256),256,0,stream>>>(A_log,   AnTF, NLAYER*DINNER*DSTATE);
  k_negexpT<<<dim3((NLAYER*DINNER*DSTATE+255)/256),256,0,stream>>>(A_log_b, AnTB, NLAYER*DINNER*DSTATE);

  const int RT16 = (NROW+15)/16;   // 103
  const int RT8  = (NROW+7)/8;     // 205
  for (int l=0; l<NLAYER; l++){
    k_normin<<<dim3(RT16,6),256,0,stream>>>(residual, norm_w + (size_t)l*DMODEL,
        WtIn + (size_t)l*DMODEL*768, xz);
    k_conv<<<dim3((NROW*(DINNER/4)+255)/256,2),256,0,stream>>>(xz,
        conv_w + (size_t)l*DINNER*KCONV, conv_b + (size_t)l*DINNER,
        conv_w_b + (size_t)l*DINNER*KCONV, conv_b_b + (size_t)l*DINNER, xf_f, xf_b);
    k_xp<<<dim3(RT8,2),256,0,stream>>>(xf_f, xf_b,
        WtXpF + (size_t)l*DINNER*44, WtXpB + (size_t)l*DINNER*44,
        WtDtF + (size_t)l*DRANK*DINNER, WtDtB + (size_t)l*DRANK*DINNER,
        dt_bias + (size_t)l*DINNER, dt_bias_b + (size_t)l*DINNER,
        dtbc_f, dtbc_b, dt_f, dt_b);
    k_scan1<<<dim3(3,BB*NCH2,2),128,0,stream>>>(xf_f, xf_b, dtbc_f, dtbc_b, dt_f, dt_b,
        AnTF + (size_t)l*DINNER*DSTATE, AnTB + (size_t)l*DINNER*DSTATE, q_buf, sdt_buf);
    k_carry<<<dim3(192),256,0,stream>>>(
        AnTF + (size_t)l*DINNER*DSTATE, AnTB + (size_t)l*DINNER*DSTATE, q_buf, sdt_buf);
    k_scan2<<<dim3(3,BB*NCH2,2),128,0,stream>>>(xf_f, xf_b, dtbc_f, dtbc_b, dt_f, dt_b,
        AnTF + (size_t)l*DINNER*DSTATE, AnTB + (size_t)l*DINNER*DSTATE,
        D_param + (size_t)l*DINNER, D_param_b + (size_t)l*DINNER,
        q_buf, y_f, y_b);
    k_out<<<dim3(RT8,3),256,0,stream>>>(y_f, y_b, xz, WtOut + (size_t)l*DINNER*DMODEL, residual);
  }
  k_final<<<dim3((NROW+3)/4),256,0,stream>>>(residual, norm_f_w, (float*)d_out);
}

// Round 4
// 2457.564 us; speedup vs baseline: 1.8932x; 1.8932x over previous
//
#include <hip/hip_runtime.h>
#include <math.h>

#define BB     4
#define LLEN   409
#define DMODEL 192
#define DINNER 384
#define DSTATE 16
#define DRANK  12
#define KCONV  4
#define NLAYER 24
#define NROW   (BB*LLEN)      /* 1636 */
#define EPSF   1e-5f
#define CH2    16             /* scan chunk length */
#define NCH2   26             /* 16*26=416 >= 409 */

__device__ __forceinline__ float siluf(float x){ return x/(1.f+__expf(-x)); }
__device__ __forceinline__ float softplusf(float x){ return (x>20.f)? x : log1pf(__expf(x)); }

// ---------------- prep kernels ----------------
__global__ void k_init(const float* __restrict__ t, float* __restrict__ r, int n){
  int i = blockIdx.x*256+threadIdx.x;
  if (i<n) r[i]=t[i];
}

// dst[l][c][r] = src[l][r][c]
__global__ void k_transpose(const float* __restrict__ src, float* __restrict__ dst, int R, int C){
  int total = NLAYER*R*C;
  for (int i = blockIdx.x*blockDim.x+threadIdx.x; i<total; i += gridDim.x*blockDim.x){
    int l = i/(R*C); int rem = i%(R*C); int r = rem/C; int c = rem%C;
    dst[((size_t)l*C + c)*R + r] = src[i];
  }
}

// padded transpose for x_proj: src [l][44][384] -> dst [l][384][64] (cols >=44 zero)
__global__ void k_xpose_pad(const float* __restrict__ src, float* __restrict__ dst){
  int total = NLAYER*DINNER*64;
  for (int i = blockIdx.x*blockDim.x+threadIdx.x; i<total; i += gridDim.x*blockDim.x){
    int l = i/(DINNER*64); int rem = i%(DINNER*64); int c = rem/64; int r = rem%64;
    dst[i] = (r<44)? src[((size_t)l*44 + r)*DINNER + c] : 0.f;
  }
}

// AnT[l][n][d] = -exp(A_log[l][d][n])
__global__ void k_negexpT(const float* __restrict__ a, float* __restrict__ o, int n){
  int i = blockIdx.x*256+threadIdx.x;
  if (i<n){
    int l = i/(DINNER*DSTATE); int rem = i%(DINNER*DSTATE);
    int d = rem/DSTATE, nn = rem%DSTATE;
    o[(size_t)l*DINNER*DSTATE + nn*DINNER + d] = -expf(a[i]);
  }
}

// ---------------- layer kernels ----------------
// RMSNorm: xn = residual * rsqrt(mean sq) * norm_w; one wave per row
__global__ __launch_bounds__(256) void k_prenorm(const float* __restrict__ residual,
    const float* __restrict__ norm_w, float* __restrict__ xn){
  int wv = threadIdx.x>>6, lane = threadIdx.x&63;
  int row = blockIdx.x*4 + wv;
  if (row >= NROW) return;
  float v[3]; float s = 0.f;
  #pragma unroll
  for (int q=0;q<3;q++){ v[q] = residual[(size_t)row*DMODEL + lane + q*64]; s += v[q]*v[q]; }
  #pragma unroll
  for (int off=1; off<64; off<<=1) s += __shfl_xor(s, off, 64);
  float sc = rsqrtf(s/(float)DMODEL + EPSF);
  #pragma unroll
  for (int q=0;q<3;q++) xn[(size_t)row*DMODEL + lane + q*64] = v[q]*sc*norm_w[lane + q*64];
}

// in_proj GEMM: xz[NROW][768] = xn[NROW][192] @ WtIn[192][768]; BM=16 BN=64; grid (103,12)
__global__ __launch_bounds__(256) void k_gemm_in(const float* __restrict__ xn,
    const float* __restrict__ Wt, float* __restrict__ xz){
  __shared__ __align__(16) float w_lds[192*64];
  __shared__ __align__(16) float a_lds[192*20];
  int tid = threadIdx.x, r0 = blockIdx.x*16, c0 = blockIdx.y*64;
  // stage W slab [192][64]
  {
    int j4 = (tid&15)*4, kr = tid>>4;
    #pragma unroll
    for (int s=0;s<12;s++){
      int k = kr + s*16;
      *reinterpret_cast<float4*>(&w_lds[k*64+j4]) =
        *reinterpret_cast<const float4*>(&Wt[(size_t)k*768 + c0 + j4]);
    }
  }
  // stage A tile [192 k][16 rows], pad 20
  {
    int i = tid>>4, kc = (tid&15)*12;
    int row = r0+i;
    #pragma unroll
    for (int m=0;m<12;m+=4){
      float4 v = make_float4(0.f,0.f,0.f,0.f);
      if (row<NROW) v = *reinterpret_cast<const float4*>(&xn[(size_t)row*192 + kc + m]);
      a_lds[(kc+m+0)*20+i]=v.x; a_lds[(kc+m+1)*20+i]=v.y;
      a_lds[(kc+m+2)*20+i]=v.z; a_lds[(kc+m+3)*20+i]=v.w;
    }
  }
  __syncthreads();
  int j = tid & 63, rg = tid >> 6;
  float acc[4] = {0.f,0.f,0.f,0.f};
  #pragma unroll 8
  for (int k=0;k<192;k++){
    float w = w_lds[k*64+j];
    float4 a = *reinterpret_cast<const float4*>(&a_lds[k*20 + rg*4]);
    acc[0]+=a.x*w; acc[1]+=a.y*w; acc[2]+=a.z*w; acc[3]+=a.w*w;
  }
  #pragma unroll
  for (int q=0;q<4;q++){
    int row = r0 + rg*4 + q;
    if (row<NROW) xz[(size_t)row*768 + c0 + j] = acc[q];
  }
}

// causal depthwise conv + bias + silu, float4 over d; grid (614, 2)
__global__ __launch_bounds__(256) void k_conv(const float* __restrict__ xz,
    const float* __restrict__ cwf, const float* __restrict__ cbf,
    const float* __restrict__ cwb, const float* __restrict__ cbb,
    float* __restrict__ xf_f, float* __restrict__ xf_b){
  int idx = blockIdx.x*256 + threadIdx.x;
  if (idx >= NROW*(DINNER/4)) return;
  int d4 = (idx % (DINNER/4))*4; int bl = idx / (DINNER/4);
  int b = bl / LLEN; int l = bl % LLEN;
  int dir = blockIdx.y;
  const float* cw = dir? cwb : cwf;
  const float* cb = dir? cbb : cbf;
  float4 w0 = *reinterpret_cast<const float4*>(&cw[(d4+0)*KCONV]);
  float4 w1 = *reinterpret_cast<const float4*>(&cw[(d4+1)*KCONV]);
  float4 w2 = *reinterpret_cast<const float4*>(&cw[(d4+2)*KCONV]);
  float4 w3 = *reinterpret_cast<const float4*>(&cw[(d4+3)*KCONV]);
  float4 acc = *reinterpret_cast<const float4*>(&cb[d4]);
  const float* wa0 = (const float*)&w0; const float* wa1 = (const float*)&w1;
  const float* wa2 = (const float*)&w2; const float* wa3 = (const float*)&w3;
  #pragma unroll
  for (int k=0;k<KCONV;k++){
    int o = dir? (LLEN-1-l-k+3) : (l-3+k);
    bool ok = dir? (l+k>=3) : (o>=0);
    if (ok){
      float4 x = *reinterpret_cast<const float4*>(&xz[((size_t)(b*LLEN+o))*768 + d4]);
      acc.x += wa0[k]*x.x; acc.y += wa1[k]*x.y; acc.z += wa2[k]*x.z; acc.w += wa3[k]*x.w;
    }
  }
  float* out = dir? xf_b : xf_f;
  float4 r; r.x = siluf(acc.x); r.y = siluf(acc.y); r.z = siluf(acc.z); r.w = siluf(acc.w);
  *reinterpret_cast<float4*>(&out[(size_t)bl*DINNER + d4]) = r;
}

// x_proj (padded to 64 cols) + dt_proj + softplus; BM=16; grid (103,1,2)
__global__ __launch_bounds__(256) void k_xp2(
    const float* __restrict__ xf_f, const float* __restrict__ xf_b,
    const float* __restrict__ WxpPF, const float* __restrict__ WxpPB,  // [384][64]
    const float* __restrict__ WdtF, const float* __restrict__ WdtB,    // [12][384]
    const float* __restrict__ dtbF, const float* __restrict__ dtbB,
    float* __restrict__ dtbc_f, float* __restrict__ dtbc_b,
    float* __restrict__ dt_f, float* __restrict__ dt_b){
  __shared__ __align__(16) float w_lds[192*64];
  __shared__ __align__(16) float a_lds[192*20];
  __shared__ float dtin_s[16*12];
  int dir = blockIdx.z;
  const float* xf  = dir? xf_b : xf_f;
  const float* Wxp = dir? WxpPB : WxpPF;
  const float* Wdt = dir? WdtB : WdtF;
  const float* dtb = dir? dtbB : dtbF;
  float* dtbc = dir? dtbc_b : dtbc_f;
  float* dtp  = dir? dt_b  : dt_f;
  int tid = threadIdx.x, r0 = blockIdx.x*16;
  int j = tid & 63, rg = tid >> 6;
  float acc[4] = {0.f,0.f,0.f,0.f};
  for (int c=0;c<2;c++){
    int K0 = c*192;
    if (c) __syncthreads();
    {
      int j4 = (tid&15)*4, kr = tid>>4;
      #pragma unroll
      for (int s=0;s<12;s++){
        int k = kr + s*16;
        *reinterpret_cast<float4*>(&w_lds[k*64+j4]) =
          *reinterpret_cast<const float4*>(&Wxp[(size_t)(K0+k)*64 + j4]);
      }
    }
    {
      int i = tid>>4, kc = (tid&15)*12;
      int row = r0+i;
      #pragma unroll
      for (int m=0;m<12;m+=4){
        float4 v = make_float4(0.f,0.f,0.f,0.f);
        if (row<NROW) v = *reinterpret_cast<const float4*>(&xf[(size_t)row*DINNER + K0 + kc + m]);
        a_lds[(kc+m+0)*20+i]=v.x; a_lds[(kc+m+1)*20+i]=v.y;
        a_lds[(kc+m+2)*20+i]=v.z; a_lds[(kc+m+3)*20+i]=v.w;
      }
    }
    __syncthreads();
    #pragma unroll 8
    for (int k=0;k<192;k++){
      float w = w_lds[k*64+j];
      float4 a = *reinterpret_cast<const float4*>(&a_lds[k*20 + rg*4]);
      acc[0]+=a.x*w; acc[1]+=a.y*w; acc[2]+=a.z*w; acc[3]+=a.w*w;
    }
  }
  __syncthreads();
  // store dtbc rows; collect dt-rank inputs
  #pragma unroll
  for (int q=0;q<4;q++){
    int i = rg*4+q, row = r0+i;
    if (j<44 && row<NROW) dtbc[(size_t)row*44 + j] = acc[q];
    if (j<12) dtin_s[i*12 + j] = acc[q];
  }
  __syncthreads();
  // stage Wdt [12][384] into w_lds
  for (int idx=tid; idx<12*DINNER; idx+=256) w_lds[idx] = Wdt[idx];
  __syncthreads();
  for (int idx=tid; idx<16*DINNER; idx+=256){
    int i = idx/DINNER, dd = idx - i*DINNER;
    int row = r0+i;
    float v = dtb[dd];
    #pragma unroll
    for (int r=0;r<12;r++) v += dtin_s[i*12+r]*w_lds[r*DINNER+dd];
    if (row<NROW) dtp[(size_t)row*DINNER+dd] = softplusf(v);
  }
}

// scan pass 1: per-chunk transfer fn; thread = one d, 16 n-states in regs
// grid (3, BB*NCH2, 2), 128 threads
__global__ __launch_bounds__(128) void k_scan1(
    const float* __restrict__ xf_f, const float* __restrict__ xf_b,
    const float* __restrict__ dtbc_f, const float* __restrict__ dtbc_b,
    const float* __restrict__ dt_f, const float* __restrict__ dt_b,
    const float* __restrict__ anF, const float* __restrict__ anB,
    float* __restrict__ q_buf, float* __restrict__ sdt_buf){
  int dir = blockIdx.z;
  int b  = blockIdx.y / NCH2;
  int ch = blockIdx.y % NCH2;
  const float* xf   = dir? xf_b  : xf_f;
  const float* dtbc = dir? dtbc_b: dtbc_f;
  const float* dtp  = dir? dt_b  : dt_f;
  const float* an   = dir? anB   : anF;
  int t0 = ch*CH2;
  int T  = (t0+CH2<=LLEN)? CH2 : (LLEN-t0);
  int d0 = blockIdx.x*128;
  size_t base = (size_t)b*LLEN + t0;
  __shared__ float dt_s[CH2*128], u_s[CH2*128];
  __shared__ __align__(16) float B_s[CH2*16];
  int tid = threadIdx.x;
  for (int t=0;t<T;t++){
    dt_s[t*128+tid] = dtp[(base+t)*DINNER + d0 + tid];
    u_s [t*128+tid] = xf [(base+t)*DINNER + d0 + tid];
  }
  for (int idx = tid; idx < T*16; idx += 128){
    int t = idx>>4, n = idx&15;
    B_s[idx] = dtbc[(base+t)*44 + 12 + n];
  }
  __syncthreads();
  int d = d0 + tid;
  float A[16], h[16];
  #pragma unroll
  for (int n=0;n<16;n++){ A[n] = an[n*DINNER + d]; h[n] = 0.f; }
  float sdt = 0.f;
  for (int t=0;t<T;t++){
    float dtv = dt_s[t*128+tid];
    float du  = dtv * u_s[t*128+tid];
    float Bv[16];
    #pragma unroll
    for (int q=0;q<4;q++) *reinterpret_cast<float4*>(&Bv[q*4]) =
        *reinterpret_cast<const float4*>(&B_s[t*16 + q*4]);
    #pragma unroll
    for (int n=0;n<16;n++) h[n] = h[n]*__expf(dtv*A[n]) + du*Bv[n];
    sdt += dtv;
  }
  size_t ci = ((size_t)dir*BB + b)*NCH2 + ch;
  float* qo = &q_buf[(ci*DINNER + d)*DSTATE];
  #pragma unroll
  for (int q=0;q<4;q++) *reinterpret_cast<float4*>(&qo[q*4]) =
      make_float4(h[q*4+0], h[q*4+1], h[q*4+2], h[q*4+3]);
  sdt_buf[ci*DINNER + d] = sdt;
}

// carry fold (in place): q_buf[ch] <- carry-in state for chunk ch
// grid (192), 256 threads; thread = (dir,b,d,n)
__global__ __launch_bounds__(256) void k_carry(
    const float* __restrict__ anF, const float* __restrict__ anB,
    float* __restrict__ q_buf, const float* __restrict__ sdt_buf){
  int g = blockIdx.x*256 + threadIdx.x;
  int n = g & 15; int r1 = g >> 4;
  int d = r1 % DINNER; int r2 = r1 / DINNER;
  int b = r2 & 3; int dir = r2 >> 2;
  const float* an = dir? anB : anF;
  float A = an[n*DINNER + d];
  size_t sbase = ((size_t)dir*BB + b)*NCH2;
  float h = 0.f;
  for (int cc=0; cc<NCH2; cc++){
    size_t qi = ((sbase+cc)*DINNER + d)*DSTATE + n;
    float qv = q_buf[qi];
    float sv = sdt_buf[(sbase+cc)*DINNER + d];
    q_buf[qi] = h;
    h = qv + __expf(A*sv)*h;
  }
}

// scan pass 2: replay chunk from carry-in, emit y; grid (3, BB*NCH2, 2), 128 thr
__global__ __launch_bounds__(128) void k_scan2(
    const float* __restrict__ xf_f, const float* __restrict__ xf_b,
    const float* __restrict__ dtbc_f, const float* __restrict__ dtbc_b,
    const float* __restrict__ dt_f, const float* __restrict__ dt_b,
    const float* __restrict__ anF, const float* __restrict__ anB,
    const float* __restrict__ DpF, const float* __restrict__ DpB,
    const float* __restrict__ q_buf,
    float* __restrict__ y_fo, float* __restrict__ y_bo){
  int dir = blockIdx.z;
  int b  = blockIdx.y / NCH2;
  int ch = blockIdx.y % NCH2;
  const float* xf   = dir? xf_b  : xf_f;
  const float* dtbc = dir? dtbc_b: dtbc_f;
  const float* dtp  = dir? dt_b  : dt_f;
  const float* an   = dir? anB   : anF;
  const float* Dp   = dir? DpB   : DpF;
  float* y = dir? y_bo : y_fo;
  int t0 = ch*CH2;
  int T  = (t0+CH2<=LLEN)? CH2 : (LLEN-t0);
  int d0 = blockIdx.x*128;
  size_t base = (size_t)b*LLEN + t0;
  __shared__ float dt_s[CH2*128], u_s[CH2*128];
  __shared__ __align__(16) float B_s[CH2*16], C_s[CH2*16];
  int tid = threadIdx.x;
  for (int t=0;t<T;t++){
    dt_s[t*128+tid] = dtp[(base+t)*DINNER + d0 + tid];
    u_s [t*128+tid] = xf [(base+t)*DINNER + d0 + tid];
  }
  for (int idx = tid; idx < T*16; idx += 128){
    int t = idx>>4, n = idx&15;
    B_s[idx] = dtbc[(base+t)*44 + 12 + n];
    C_s[idx] = dtbc[(base+t)*44 + 28 + n];
  }
  __syncthreads();
  int d = d0 + tid;
  size_t ci = ((size_t)dir*BB + b)*NCH2 + ch;
  const float* qi = &q_buf[(ci*DINNER + d)*DSTATE];
  float A[16], h[16];
  #pragma unroll
  for (int q=0;q<4;q++){
    float4 hv = *reinterpret_cast<const float4*>(&qi[q*4]);
    h[q*4+0]=hv.x; h[q*4+1]=hv.y; h[q*4+2]=hv.z; h[q*4+3]=hv.w;
  }
  #pragma unroll
  for (int n=0;n<16;n++) A[n] = an[n*DINNER + d];
  float Dd = Dp[d];
  for (int t=0;t<T;t++){
    float dtv = dt_s[t*128+tid];
    float u   = u_s [t*128+tid];
    float du  = dtv*u;
    float Bv[16], Cv[16];
    #pragma unroll
    for (int q=0;q<4;q++){
      *reinterpret_cast<float4*>(&Bv[q*4]) = *reinterpret_cast<const float4*>(&B_s[t*16+q*4]);
      *reinterpret_cast<float4*>(&Cv[q*4]) = *reinterpret_cast<const float4*>(&C_s[t*16+q*4]);
    }
    float y0=0.f, y1=0.f, y2=0.f, y3=0.f;
    #pragma unroll
    for (int n=0;n<16;n+=4){
      h[n+0] = h[n+0]*__expf(dtv*A[n+0]) + du*Bv[n+0];
      h[n+1] = h[n+1]*__expf(dtv*A[n+1]) + du*Bv[n+1];
      h[n+2] = h[n+2]*__expf(dtv*A[n+2]) + du*Bv[n+2];
      h[n+3] = h[n+3]*__expf(dtv*A[n+3]) + du*Bv[n+3];
      y0 += h[n+0]*Cv[n+0]; y1 += h[n+1]*Cv[n+1];
      y2 += h[n+2]*Cv[n+2]; y3 += h[n+3]*Cv[n+3];
    }
    y[(base+t)*DINNER + d] = (y0+y1)+(y2+y3) + u*Dd;
  }
}

// gate: g = (y_f + y_b(reversed)) * silu(z) * 0.5; grid (614)
__global__ __launch_bounds__(256) void k_gate(
    const float* __restrict__ y_f, const float* __restrict__ y_b,
    const float* __restrict__ xz, float* __restrict__ g){
  int idx = blockIdx.x*256 + threadIdx.x;
  if (idx >= NROW*(DINNER/4)) return;
  int d4 = (idx % (DINNER/4))*4; int row = idx / (DINNER/4);
  int b = row/LLEN, l = row%LLEN;
  int rrow = b*LLEN + (LLEN-1-l);
  float4 yf = *reinterpret_cast<const float4*>(&y_f[(size_t)row*DINNER + d4]);
  float4 yb = *reinterpret_cast<const float4*>(&y_b[(size_t)rrow*DINNER + d4]);
  float4 z  = *reinterpret_cast<const float4*>(&xz[(size_t)row*768 + DINNER + d4]);
  float4 r;
  r.x = (yf.x+yb.x)*siluf(z.x)*0.5f; r.y = (yf.y+yb.y)*siluf(z.y)*0.5f;
  r.z = (yf.z+yb.z)*siluf(z.z)*0.5f; r.w = (yf.w+yb.w)*siluf(z.w)*0.5f;
  *reinterpret_cast<float4*>(&g[(size_t)row*DINNER + d4]) = r;
}

// out_proj GEMM: residual += g[NROW][384] @ WtOut[384][192]; BM=16 BN=64; grid (103,3)
__global__ __launch_bounds__(256) void k_gemm_out(const float* __restrict__ g,
    const float* __restrict__ Wt, float* __restrict__ residual){
  __shared__ __align__(16) float w_lds[192*64];
  __shared__ __align__(16) float a_lds[192*20];
  int tid = threadIdx.x, r0 = blockIdx.x*16, c0 = blockIdx.y*64;
  int j = tid & 63, rg = tid >> 6;
  float acc[4] = {0.f,0.f,0.f,0.f};
  for (int c=0;c<2;c++){
    int K0 = c*192;
    if (c) __syncthreads();
    {
      int j4 = (tid&15)*4, kr = tid>>4;
      #pragma unroll
      for (int s=0;s<12;s++){
        int k = kr + s*16;
        *reinterpret_cast<float4*>(&w_lds[k*64+j4]) =
          *reinterpret_cast<const float4*>(&Wt[(size_t)(K0+k)*192 + c0 + j4]);
      }
    }
    {
      int i = tid>>4, kc = (tid&15)*12;
      int row = r0+i;
      #pragma unroll
      for (int m=0;m<12;m+=4){
        float4 v = make_float4(0.f,0.f,0.f,0.f);
        if (row<NROW) v = *reinterpret_cast<const float4*>(&g[(size_t)row*DINNER + K0 + kc + m]);
        a_lds[(kc+m+0)*20+i]=v.x; a_lds[(kc+m+1)*20+i]=v.y;
        a_lds[(kc+m+2)*20+i]=v.z; a_lds[(kc+m+3)*20+i]=v.w;
      }
    }
    __syncthreads();
    #pragma unroll 8
    for (int k=0;k<192;k++){
      float w = w_lds[k*64+j];
      float4 a = *reinterpret_cast<const float4*>(&a_lds[k*20 + rg*4]);
      acc[0]+=a.x*w; acc[1]+=a.y*w; acc[2]+=a.z*w; acc[3]+=a.w*w;
    }
  }
  #pragma unroll
  for (int q=0;q<4;q++){
    int row = r0 + rg*4 + q;
    if (row<NROW) residual[(size_t)row*DMODEL + c0 + j] += acc[q];
  }
}

// final RMSNorm -> d_out
__global__ __launch_bounds__(256) void k_final(const float* __restrict__ residual,
    const float* __restrict__ nfw, float* __restrict__ out){
  int wv = threadIdx.x>>6, lane = threadIdx.x&63;
  int row = blockIdx.x*4 + wv;
  if (row >= NROW) return;
  float v[3]; float s = 0.f;
  #pragma unroll
  for (int q=0;q<3;q++){ v[q] = residual[(size_t)row*DMODEL + lane + q*64]; s += v[q]*v[q]; }
  #pragma unroll
  for (int off=1; off<64; off<<=1) s += __shfl_xor(s, off, 64);
  float sc = rsqrtf(s/(float)DMODEL + EPSF);
  #pragma unroll
  for (int q=0;q<3;q++) out[(size_t)row*DMODEL + lane + q*64] = v[q]*sc*nfw[lane + q*64];
}

// ---------------- host ----------------
extern "C" void kernel_launch(void* const* d_in, const int* in_sizes, int n_in,
                              void* d_out, int out_size, void* d_ws, size_t ws_size,
                              hipStream_t stream){
  const float* tokens     = (const float*)d_in[0];
  const float* norm_w     = (const float*)d_in[1];
  const float* in_proj_w  = (const float*)d_in[2];
  const float* conv_w     = (const float*)d_in[3];
  const float* conv_b     = (const float*)d_in[4];
  const float* conv_w_b   = (const float*)d_in[5];
  const float* conv_b_b   = (const float*)d_in[6];
  const float* x_proj_w   = (const float*)d_in[7];
  const float* x_proj_w_b = (const float*)d_in[8];
  const float* dt_proj_w  = (const float*)d_in[9];
  const float* dt_bias    = (const float*)d_in[10];
  const float* dt_proj_w_b= (const float*)d_in[11];
  const float* dt_bias_b  = (const float*)d_in[12];
  const float* A_log      = (const float*)d_in[13];
  const float* A_log_b    = (const float*)d_in[14];
  const float* D_param    = (const float*)d_in[15];
  const float* D_param_b  = (const float*)d_in[16];
  const float* out_proj_w = (const float*)d_in[17];
  const float* norm_f_w   = (const float*)d_in[18];

  float* ws = (float*)d_ws;
  size_t off = 0;
  float* residual = ws + off; off += (size_t)NROW*DMODEL;
  float* xn       = ws + off; off += (size_t)NROW*DMODEL;
  float* xz       = ws + off; off += (size_t)NROW*768;
  float* xf_f     = ws + off; off += (size_t)NROW*DINNER;
  float* xf_b     = ws + off; off += (size_t)NROW*DINNER;
  float* dtbc_f   = ws + off; off += (size_t)NROW*44;
  float* dtbc_b   = ws + off; off += (size_t)NROW*44;
  float* dt_f     = ws + off; off += (size_t)NROW*DINNER;
  float* dt_b     = ws + off; off += (size_t)NROW*DINNER;
  float* y_f      = ws + off; off += (size_t)NROW*DINNER;
  float* y_b      = ws + off; off += (size_t)NROW*DINNER;
  float* gbuf     = ws + off; off += (size_t)NROW*DINNER;
  float* q_buf    = ws + off; off += (size_t)2*BB*NCH2*DINNER*DSTATE;
  float* sdt_buf  = ws + off; off += (size_t)2*BB*NCH2*DINNER;
  float* WtIn     = ws + off; off += (size_t)NLAYER*DMODEL*768;
  float* WtXpPF   = ws + off; off += (size_t)NLAYER*DINNER*64;
  float* WtXpPB   = ws + off; off += (size_t)NLAYER*DINNER*64;
  float* WtDtF    = ws + off; off += (size_t)NLAYER*DRANK*DINNER;
  float* WtDtB    = ws + off; off += (size_t)NLAYER*DRANK*DINNER;
  float* WtOut    = ws + off; off += (size_t)NLAYER*DINNER*DMODEL;
  float* AnTF     = ws + off; off += (size_t)NLAYER*DINNER*DSTATE;
  float* AnTB     = ws + off; off += (size_t)NLAYER*DINNER*DSTATE;
  if (off*sizeof(float) > ws_size) return;   // workspace too small: fail loudly

  // prep
  k_init<<<dim3((NROW*DMODEL+255)/256),256,0,stream>>>(tokens, residual, NROW*DMODEL);
  k_transpose<<<2048,256,0,stream>>>(in_proj_w,  WtIn,  768, DMODEL);
  k_xpose_pad<<<1024,256,0,stream>>>(x_proj_w,   WtXpPF);
  k_xpose_pad<<<1024,256,0,stream>>>(x_proj_w_b, WtXpPB);
  k_transpose<<<512, 256,0,stream>>>(dt_proj_w,  WtDtF, DINNER, DRANK);
  k_transpose<<<512, 256,0,stream>>>(dt_proj_w_b,WtDtB, DINNER, DRANK);
  k_transpose<<<2048,256,0,stream>>>(out_proj_w, WtOut, DMODEL, DINNER);
  k_negexpT<<<dim3((NLAYER*DINNER*DSTATE+255)/256),256,0,stream>>>(A_log,   AnTF, NLAYER*DINNER*DSTATE);
  k_negexpT<<<dim3((NLAYER*DINNER*DSTATE+255)/256),256,0,stream>>>(A_log_b, AnTB, NLAYER*DINNER*DSTATE);

  const int RT16 = (NROW+15)/16;            // 103
  const int EW4  = (NROW*(DINNER/4)+255)/256; // 614
  for (int l=0; l<NLAYER; l++){
    k_prenorm<<<dim3((NROW+3)/4),256,0,stream>>>(residual, norm_w + (size_t)l*DMODEL, xn);
    k_gemm_in<<<dim3(RT16,12),256,0,stream>>>(xn, WtIn + (size_t)l*DMODEL*768, xz);
    k_conv<<<dim3(EW4,2),256,0,stream>>>(xz,
        conv_w + (size_t)l*DINNER*KCONV, conv_b + (size_t)l*DINNER,
        conv_w_b + (size_t)l*DINNER*KCONV, conv_b_b + (size_t)l*DINNER, xf_f, xf_b);
    k_xp2<<<dim3(RT16,1,2),256,0,stream>>>(xf_f, xf_b,
        WtXpPF + (size_t)l*DINNER*64, WtXpPB + (size_t)l*DINNER*64,
        WtDtF + (size_t)l*DRANK*DINNER, WtDtB + (size_t)l*DRANK*DINNER,
        dt_bias + (size_t)l*DINNER, dt_bias_b + (size_t)l*DINNER,
        dtbc_f, dtbc_b, dt_f, dt_b);
    k_scan1<<<dim3(3,BB*NCH2,2),128,0,stream>>>(xf_f, xf_b, dtbc_f, dtbc_b, dt_f, dt_b,
        AnTF + (size_t)l*DINNER*DSTATE, AnTB + (size_t)l*DINNER*DSTATE, q_buf, sdt_buf);
    k_carry<<<dim3(192),256,0,stream>>>(
        AnTF + (size_t)l*DINNER*DSTATE, AnTB + (size_t)l*DINNER*DSTATE, q_buf, sdt_buf);
    k_scan2<<<dim3(3,BB*NCH2,2),128,0,stream>>>(xf_f, xf_b, dtbc_f, dtbc_b, dt_f, dt_b,
        AnTF + (size_t)l*DINNER*DSTATE, AnTB + (size_t)l*DINNER*DSTATE,
        D_param + (size_t)l*DINNER, D_param_b + (size_t)l*DINNER,
        q_buf, y_f, y_b);
    k_gate<<<dim3(EW4),256,0,stream>>>(y_f, y_b, xz, gbuf);
    k_gemm_out<<<dim3(RT16,3),256,0,stream>>>(gbuf, WtOut + (size_t)l*DINNER*DMODEL, residual);
  }
  k_final<<<dim3((NROW+3)/4),256,0,stream>>>(residual, norm_f_w, (float*)d_out);
}